// Round 8
// baseline (1352.855 us; speedup 1.0000x reference)
//
#include <hip/hip_runtime.h>

// ---------------------------------------------------------------------------
// CellVGAE GCN encoder: x -> GCN(512,128)+ReLU -> GCN(128,128)+ReLU
//                         -> {GCN(128,64) mean, GCN(128,64) log_std}
// Round 13: FULL FUSION. Evidence: per-kernel sums ~290us vs 488us wall ->
//   ~150-200us is inter-dispatch overhead (13 graph nodes). Fuse all compute
//   into ONE persistent kernel (768 blocks = 3/CU, co-residency guaranteed
//   by __launch_bounds__(256,3): VGPR<=168 -> >=3 blocks/CU; LDS 9.3KB).
//   Generation-counting software grid barrier, device-scope atomics +
//   __threadfence (cross-XCD per guide G16/m20). Phase math = r12 verbatim
//   (passed, absmax 0.001953125): per-phase geometry and op order identical.
//   Graph: 2 nodes (memset 200KB, fused kernel).
// ---------------------------------------------------------------------------

using u16 = unsigned short;
typedef __attribute__((ext_vector_type(8))) short short8;
typedef __attribute__((ext_vector_type(4))) float f32x4;

__device__ __forceinline__ void split_bf16(float f, u16& hi, u16& lo) {
    unsigned b = __float_as_uint(f);
    hi = (u16)(b >> 16);
    float rem = f - __uint_as_float(b & 0xFFFF0000u);
    lo = (u16)(__float_as_uint(rem) >> 16);
}

#define TILE_OFF(t) ((t) * 520)

// Generation-counting grid barrier. Requires all blocks co-resident.
// cnt self-resets BEFORE gen bump -> reusable, replay-safe (any start gen).
__device__ __forceinline__ void gbar(int* cnt, int* gen, int nb) {
    __syncthreads();
    if (threadIdx.x == 0) {
        __threadfence();                          // release this block's writes
        int g = atomicAdd(gen, 0);                // read generation (device scope)
        if (atomicAdd(cnt, 1) == nb - 1) {
            atomicExch(cnt, 0);                   // reset before release
            atomicAdd(gen, 1);                    // release all
        } else {
            while (atomicAdd(gen, 0) == g) __builtin_amdgcn_s_sleep(2);
        }
        __threadfence();                          // acquire others' writes
    }
    __syncthreads();
}

// ---- GEMM tile: C[64 x 128] block = dis (.) (A @ B), r12-verbatim body ----
// A via LDS (lane-sequential map, conflicts=0 measured); B frags direct from
// global in MFMA fragment order (L2-hot). Frag: lane L: row/col (L&15),
// k=(L>>4)*8..+8; C/D: col=lane&15, row=(lane>>4)*4+reg.
__device__ __forceinline__ void gemm_tile(
    const float* __restrict__ A, const u16* __restrict__ Bfh,
    const u16* __restrict__ Bfl, const float* __restrict__ dis,
    float* __restrict__ C, int N, int K, int tile,
    u16* AsH, u16* AsL) {
    const int tid = threadIdx.x;
    const int w = tid >> 6, lane = tid & 63;
    const int m16 = lane & 15, quad = lane >> 4;
    const int row0 = tile * 64;

    const int s_ar = w * 16 + (lane & 15);
    const int s_ak = (lane >> 4) * 8;
    const int a_dst = TILE_OFF(w) + lane * 8;

    const int R = (w >> 1) * 32, Cc = (w & 1) * 64;
    const int atile = (w >> 1) * 2;
    const int btile = (w & 1) * 4;

    const int ksteps = K >> 5;
    const u16* bfh = Bfh + ((size_t)btile * ksteps) * 512 + lane * 8;
    const u16* bfl = Bfl + ((size_t)btile * ksteps) * 512 + lane * 8;

    f32x4 acc[2][4];
#pragma unroll
    for (int i = 0; i < 2; ++i)
#pragma unroll
        for (int j = 0; j < 4; ++j) acc[i][j] = (f32x4)0.f;

    float dr[2][4];
#pragma unroll
    for (int i = 0; i < 2; ++i)
#pragma unroll
        for (int r = 0; r < 4; ++r) {
            int gr = row0 + R + i * 16 + quad * 4 + r;
            dr[i][r] = dis[gr < N ? gr : N - 1];
        }

    const int grow = row0 + s_ar;
    const bool ok = (grow < N);
    const float* aptr = A + (size_t)grow * K + s_ak;

    float av[8];
    {
        f32x4 v0 = (f32x4)0.f, v1 = (f32x4)0.f;
        if (ok) { v0 = *(const f32x4*)&aptr[0]; v1 = *(const f32x4*)&aptr[4]; }
#pragma unroll
        for (int q = 0; q < 4; ++q) { av[q] = v0[q]; av[4 + q] = v1[q]; }
    }

    for (int ks = 0; ks < ksteps; ++ks) {
        short8 fbh[4], fbl[4];
#pragma unroll
        for (int j = 0; j < 4; ++j) {
            fbh[j] = *(const short8*)(bfh + (size_t)(j * ksteps + ks) * 512);
            fbl[j] = *(const short8*)(bfl + (size_t)(j * ksteps + ks) * 512);
        }

        short8 ah, al;
#pragma unroll
        for (int q = 0; q < 8; ++q) {
            u16 h, l;
            split_bf16(av[q], h, l);
            ah[q] = (short)h;
            al[q] = (short)l;
        }
        __syncthreads();
        *(short8*)&AsH[a_dst] = ah;
        *(short8*)&AsL[a_dst] = al;
        __syncthreads();

        if (ks + 1 < ksteps) {
            const int k0 = (ks + 1) * 32;
            f32x4 v0 = (f32x4)0.f, v1 = (f32x4)0.f;
            if (ok) { v0 = *(const f32x4*)&aptr[k0]; v1 = *(const f32x4*)&aptr[k0 + 4]; }
#pragma unroll
            for (int q = 0; q < 4; ++q) { av[q] = v0[q]; av[4 + q] = v1[q]; }
        }

        short8 fah[2], fal[2];
#pragma unroll
        for (int i = 0; i < 2; ++i) {
            fah[i] = *(const short8*)&AsH[TILE_OFF(atile + i) + lane * 8];
            fal[i] = *(const short8*)&AsL[TILE_OFF(atile + i) + lane * 8];
        }

#pragma unroll
        for (int i = 0; i < 2; ++i)
#pragma unroll
            for (int j = 0; j < 4; ++j) {
                acc[i][j] = __builtin_amdgcn_mfma_f32_16x16x32_bf16(
                    fah[i], fbh[j], acc[i][j], 0, 0, 0);
                acc[i][j] = __builtin_amdgcn_mfma_f32_16x16x32_bf16(
                    fah[i], fbl[j], acc[i][j], 0, 0, 0);
                acc[i][j] = __builtin_amdgcn_mfma_f32_16x16x32_bf16(
                    fal[i], fbh[j], acc[i][j], 0, 0, 0);
            }
    }

#pragma unroll
    for (int i = 0; i < 2; ++i) {
#pragma unroll
        for (int r = 0; r < 4; ++r) {
            int gr = row0 + R + i * 16 + quad * 4 + r;
            if (gr < N) {
#pragma unroll
                for (int j = 0; j < 4; ++j)
                    C[(size_t)gr * 128 + Cc + j * 16 + m16] = acc[i][j][r] * dr[i][r];
            }
        }
    }
}

// ---- propagate phase (r12-verbatim math, grid-stride over nodes) ----------
__device__ __forceinline__ void prop_std(
    const float* __restrict__ hs, const int* __restrict__ rowptr,
    const int* __restrict__ csr_src, const float* __restrict__ dis,
    const float* __restrict__ bias, float* __restrict__ o, int N,
    int do_relu, int nwaves) {
    const int lane = threadIdx.x & 63;
    const int half = lane >> 5, c = lane & 31;
    const int f4 = c * 4;
    const int w0 = ((int)blockIdx.x * 256 + (int)threadIdx.x) >> 6;
    for (int v = w0; v < N; v += nwaves) {
        const float dv = dis[v];
        f32x4 acc = (f32x4)0.f;
        const int beg = rowptr[v], end = rowptr[v + 1];
        int i = beg;
        for (; i + 8 <= end; i += 8) {
            int s[4];
            f32x4 g[4];
#pragma unroll
            for (int u = 0; u < 4; ++u) s[u] = csr_src[i + 2 * u + half];
#pragma unroll
            for (int u = 0; u < 4; ++u) g[u] = *(const f32x4*)&hs[(size_t)s[u] * 128 + f4];
#pragma unroll
            for (int u = 0; u < 4; ++u) acc += g[u];
        }
        for (; i + 2 <= end; i += 2) {
            int s = csr_src[i + half];
            acc += *(const f32x4*)&hs[(size_t)s * 128 + f4];
        }
        if (i < end && half == 0) {
            int s = csr_src[i];
            acc += *(const f32x4*)&hs[(size_t)s * 128 + f4];
        }
#pragma unroll
        for (int k = 0; k < 4; ++k) acc[k] += __shfl_xor(acc[k], 32);
        if (half == 0) {
            const f32x4 hv = *(const f32x4*)&hs[(size_t)v * 128 + f4];
            const f32x4 b = *(const f32x4*)&bias[f4];
            f32x4 oo;
#pragma unroll
            for (int k = 0; k < 4; ++k) {
                float t = dv * (acc[k] + hv[k]) + b[k];
                oo[k] = do_relu ? fmaxf(t, 0.f) : t;
            }
            *(f32x4*)&o[(size_t)v * 128 + f4] = oo;
        }
    }
}

__device__ __forceinline__ void prop_fin(
    const float* __restrict__ hs, const int* __restrict__ rowptr,
    const int* __restrict__ csr_src, const float* __restrict__ dis,
    const float* __restrict__ bm, const float* __restrict__ bs,
    float* __restrict__ o, int N, int nwaves) {
    const int lane = threadIdx.x & 63;
    const int half = lane >> 5, c = lane & 31;
    const int f4 = c * 4;
    const int w0 = ((int)blockIdx.x * 256 + (int)threadIdx.x) >> 6;
    for (int v = w0; v < N; v += nwaves) {
        const float dv = dis[v];
        f32x4 acc = (f32x4)0.f;
        const int beg = rowptr[v], end = rowptr[v + 1];
        int i = beg;
        for (; i + 8 <= end; i += 8) {
            int s[4];
            f32x4 g[4];
#pragma unroll
            for (int u = 0; u < 4; ++u) s[u] = csr_src[i + 2 * u + half];
#pragma unroll
            for (int u = 0; u < 4; ++u) g[u] = *(const f32x4*)&hs[(size_t)s[u] * 128 + f4];
#pragma unroll
            for (int u = 0; u < 4; ++u) acc += g[u];
        }
        for (; i + 2 <= end; i += 2) {
            int s = csr_src[i + half];
            acc += *(const f32x4*)&hs[(size_t)s * 128 + f4];
        }
        if (i < end && half == 0) {
            int s = csr_src[i];
            acc += *(const f32x4*)&hs[(size_t)s * 128 + f4];
        }
#pragma unroll
        for (int k = 0; k < 4; ++k) acc[k] += __shfl_xor(acc[k], 32);
        if (half == 0) {
            const f32x4 hv = *(const f32x4*)&hs[(size_t)v * 128 + f4];
            f32x4 oo;
            if (f4 < 64) {
                const f32x4 b = *(const f32x4*)&bm[f4];
#pragma unroll
                for (int k = 0; k < 4; ++k) oo[k] = dv * (acc[k] + hv[k]) + b[k];
                *(f32x4*)&o[(size_t)v * 64 + f4] = oo;
            } else {
                const int g = f4 - 64;
                const f32x4 b = *(const f32x4*)&bs[g];
#pragma unroll
                for (int k = 0; k < 4; ++k) oo[k] = dv * (acc[k] + hv[k]) + b[k];
                *(f32x4*)&o[(size_t)N * 64 + (size_t)v * 64 + g] = oo;
            }
        }
    }
}

// ---- the fused kernel -----------------------------------------------------
__global__ __launch_bounds__(256, 3) void fused_all(
    const float* __restrict__ x, const int* __restrict__ ew,
    const float* __restrict__ W1, const float* __restrict__ b1,
    const float* __restrict__ W2, const float* __restrict__ b2,
    const float* __restrict__ Wm, const float* __restrict__ bm,
    const float* __restrict__ Ws, const float* __restrict__ bs,
    int* cnt, int* gen, int* deg, int* cursor, float* dis,
    int* rowptr, int* aux, int* csr_src,
    u16* B1h, u16* B1l, u16* B2h, u16* B2l, u16* Bch, u16* Bcl,
    float* hA, float* hB, float* out, int N, int E) {
    __shared__ __align__(16) u16 AsH[4 * 520], AsL[4 * 520];
    __shared__ int sint[257];

    const int tid = threadIdx.x;
    const int bid = blockIdx.x;
    const int NB = gridDim.x;
    const int gtid = bid * 256 + tid;
    const int GT = NB * 256;
    const int nwaves = NB * 4;

    // mode detect: 1 = int64 edge_index, 0 = int32
    int mode;
    {
        if (tid == 0) sint[256] = 0;
        __syncthreads();
        if (ew[2 * tid + 1] != 0) atomicOr(&sint[256], 1);
        __syncthreads();
        mode = sint[256] ? 0 : 1;
        __syncthreads();
    }

    // P0: weight conversion (frag order) + degree count
    if (gtid < 98304) {
        int idx = gtid;
        u16 h, l;
        if (idx < 65536) {                 // W1: 512x128, ksteps=16
            int t = idx >> 13, ks = (idx >> 9) & 15, L = (idx >> 3) & 63, q = idx & 7;
            int col = t * 16 + (L & 15);
            int k = ks * 32 + (L >> 4) * 8 + q;
            split_bf16(W1[k * 128 + col], h, l);
            B1h[idx] = h; B1l[idx] = l;
        } else if (idx < 81920) {          // W2: 128x128, ksteps=4
            int o = idx - 65536;
            int t = o >> 11, ks = (o >> 9) & 3, L = (o >> 3) & 63, q = o & 7;
            int col = t * 16 + (L & 15);
            int k = ks * 32 + (L >> 4) * 8 + q;
            split_bf16(W2[k * 128 + col], h, l);
            B2h[o] = h; B2l[o] = l;
        } else {                           // [Wm|Ws]: 128x128, ksteps=4
            int o = idx - 81920;
            int t = o >> 11, ks = (o >> 9) & 3, L = (o >> 3) & 63, q = o & 7;
            int col = t * 16 + (L & 15);
            int k = ks * 32 + (L >> 4) * 8 + q;
            float f = (col < 64) ? Wm[k * 64 + col] : Ws[k * 64 + (col - 64)];
            split_bf16(f, h, l);
            Bch[o] = h; Bcl[o] = l;
        }
    }
    for (int e = gtid; e < E; e += GT) {
        int d = mode ? ew[2 * E + 2 * e] : ew[E + e];
        atomicAdd(&deg[d], 1);
    }
    gbar(cnt, gen, NB);

    // P1: per-chunk exclusive scan + dis = rsqrt(deg+1)
    const int nch = (N + 255) >> 8;
    for (int ch = bid; ch < nch; ch += NB) {
        int i = ch * 256 + tid;
        int v = (i < N) ? deg[i] : 0;
        if (i < N) dis[i] = rsqrtf((float)v + 1.0f);
        sint[tid] = v;
        __syncthreads();
        for (int off = 1; off < 256; off <<= 1) {
            int t = (tid >= off) ? sint[tid - off] : 0;
            __syncthreads();
            sint[tid] += t;
            __syncthreads();
        }
        if (i < N) rowptr[i] = sint[tid] - v;
        if (tid == 255) aux[ch] = sint[255];
        __syncthreads();
    }
    gbar(cnt, gen, NB);

    // P2: aux scan (block 0)
    if (bid == 0) {
        int v = (tid < nch) ? aux[tid] : 0;
        sint[tid] = v;
        __syncthreads();
        for (int off = 1; off < 256; off <<= 1) {
            int t = (tid >= off) ? sint[tid - off] : 0;
            __syncthreads();
            sint[tid] += t;
            __syncthreads();
        }
        if (tid < nch) aux[tid] = sint[tid] - v;
    }
    gbar(cnt, gen, NB);

    // P3: finalize rowptr + cursor init
    for (int i = gtid; i < N; i += GT) {
        int rp = rowptr[i] + aux[i >> 8];
        rowptr[i] = rp;
        cursor[i] = rp;
    }
    if (gtid == 0) rowptr[N] = E;
    gbar(cnt, gen, NB);

    // P4: CSR fill
    for (int e = gtid; e < E; e += GT) {
        int s = mode ? ew[2 * e] : ew[e];
        int d = mode ? ew[2 * E + 2 * e] : ew[E + e];
        int pos = atomicAdd(&cursor[d], 1);
        csr_src[pos] = s;
    }
    gbar(cnt, gen, NB);

    const int ntiles = (N + 63) >> 6;

    // P5: GEMM1 (K=512): hA = dis (.) (x @ W1)
    for (int t = bid; t < ntiles; t += NB)
        gemm_tile(x, B1h, B1l, dis, hA, N, 512, t, AsH, AsL);
    gbar(cnt, gen, NB);

    // P6: prop1 -> hB (relu)
    prop_std(hA, rowptr, csr_src, dis, b1, hB, N, 1, nwaves);
    gbar(cnt, gen, NB);

    // P7: GEMM2 (K=128): hA = dis (.) (hB @ W2)
    for (int t = bid; t < ntiles; t += NB)
        gemm_tile(hB, B2h, B2l, dis, hA, N, 128, t, AsH, AsL);
    gbar(cnt, gen, NB);

    // P8: prop2 -> hB (relu)
    prop_std(hA, rowptr, csr_src, dis, b2, hB, N, 1, nwaves);
    gbar(cnt, gen, NB);

    // P9: GEMM3 (K=128): hA = dis (.) (hB @ [Wm|Ws])
    for (int t = bid; t < ntiles; t += NB)
        gemm_tile(hB, Bch, Bcl, dis, hA, N, 128, t, AsH, AsL);
    gbar(cnt, gen, NB);

    // P10: final prop -> out {z_mean, z_log_std}
    prop_fin(hA, rowptr, csr_src, dis, bm, bs, out, N, nwaves);
}

extern "C" void kernel_launch(void* const* d_in, const int* in_sizes, int n_in,
                              void* d_out, int out_size, void* d_ws, size_t ws_size,
                              hipStream_t stream) {
    const float* x  = (const float*)d_in[0];
    const int*   ew = (const int*)d_in[1];
    const float* W1 = (const float*)d_in[2];
    const float* b1 = (const float*)d_in[3];
    const float* W2 = (const float*)d_in[4];
    const float* b2 = (const float*)d_in[5];
    const float* Wm = (const float*)d_in[6];
    const float* bm = (const float*)d_in[7];
    const float* Ws = (const float*)d_in[8];
    const float* bs = (const float*)d_in[9];
    float* out = (float*)d_out;

    const int IN = 512, H = 128;
    const int N = in_sizes[0] / IN;     // 50000
    const int E = in_sizes[1] / 2;      // 800000

    // ---- workspace (~55.6 MB < proven-safe 58.47 MB) -----------------------
    char* base = (char*)d_ws;
    size_t off = 0;
    auto alloc = [&](size_t bytes) -> char* {
        char* p = base + off;
        off = (off + bytes + 255) & ~(size_t)255;
        return p;
    };
    int*   sync2   = (int*)  alloc(256);                // cnt, gen (zeroed)
    int*   deg     = (int*)  alloc((size_t)N * 4);      // zeroed
    int*   cursor  = (int*)  alloc((size_t)N * 4);      // init in P3
    float* dis     = (float*)alloc((size_t)N * 4);
    int*   rowptr  = (int*)  alloc((size_t)(N + 1) * 4);
    int*   aux     = (int*)  alloc(256 * 4);
    int*   csr_src = (int*)  alloc((size_t)E * 4);
    u16*   B1h     = (u16*)  alloc((size_t)IN * H * 2);
    u16*   B1l     = (u16*)  alloc((size_t)IN * H * 2);
    u16*   B2h     = (u16*)  alloc((size_t)H * H * 2);
    u16*   B2l     = (u16*)  alloc((size_t)H * H * 2);
    u16*   Bch     = (u16*)  alloc((size_t)H * H * 2);
    u16*   Bcl     = (u16*)  alloc((size_t)H * H * 2);
    float* hA      = (float*)alloc((size_t)N * H * 4);
    float* hB      = (float*)alloc((size_t)N * H * 4);
    (void)ws_size; (void)n_in; (void)out_size;

    // zero {cnt,gen} + deg in one contiguous memset (re-run every launch)
    size_t zlen = (size_t)((char*)cursor - (char*)sync2);
    hipMemsetAsync(sync2, 0, zlen, stream);

    // one persistent kernel: 768 blocks = 3 blocks/CU exactly (co-resident
    // by __launch_bounds__(256,3): VGPR<=168 -> >=3 blocks/CU; LDS 9.3KB)
    fused_all<<<768, 256, 0, stream>>>(
        x, ew, W1, b1, W2, b2, Wm, bm, Ws, bs,
        &sync2[0], &sync2[1], deg, cursor, dis, rowptr, aux, csr_src,
        B1h, B1l, B2h, B2l, Bch, Bcl, hA, hB, out, N, E);
}

// Round 9
// 451.769 us; speedup vs baseline: 2.9946x; 2.9946x over previous
//
#include <hip/hip_runtime.h>

// ---------------------------------------------------------------------------
// CellVGAE GCN encoder: x -> GCN(512,128)+ReLU -> GCN(128,128)+ReLU
//                         -> {GCN(128,64) mean, GCN(128,64) log_std}
// Round 14: revert full fusion (r13: 3x regression — latency-bound phases
//   need their own high-occupancy grids). Base = r12 (passed, 488us).
//   Dependency-graph consolidation only:
//   - conv + deg fused (independent work, one dispatch).
//   - scan_aux folded into offsets (each block redundantly scans 196-entry
//     aux in LDS; removes a node + a serial dep).
//   - fill_csr rides inside the gemm1 dispatch (mixed-role grid): blocks
//     0..gtiles-1 compute gemm tiles, the rest fill CSR. Only legal
//     intra-stream overlap; fill hides under gemm1.
//   13 -> 10 graph nodes. All phase math r12-verbatim -> absmax unchanged.
// ---------------------------------------------------------------------------

using u16 = unsigned short;
typedef __attribute__((ext_vector_type(8))) short short8;
typedef __attribute__((ext_vector_type(4))) float f32x4;

__device__ __forceinline__ void split_bf16(float f, u16& hi, u16& lo) {
    unsigned b = __float_as_uint(f);
    hi = (u16)(b >> 16);
    float rem = f - __uint_as_float(b & 0xFFFF0000u);
    lo = (u16)(__float_as_uint(rem) >> 16);
}

#define TILE_OFF(t) ((t) * 520)

// Block-wide mode detect: 1 = int64 edge_index, 0 = int32.
__device__ __forceinline__ int block_mode(const int* __restrict__ ew, int* sflag) {
    if (threadIdx.x == 0) *sflag = 0;
    __syncthreads();
    if (ew[2 * (int)threadIdx.x + 1] != 0) atomicOr(sflag, 1);
    __syncthreads();
    return *sflag ? 0 : 1;
}

// ---- GEMM tile: C[64 x 128] block = dis (.) (A @ B) -----------------------
// r12-verbatim body (validated bit-exact in r12/r13). A via LDS (lane-seq
// map, conflicts=0); B frags direct from global in MFMA fragment order.
// Frag: lane L: row/col (L&15), k=(L>>4)*8..+8; C/D: col=lane&15,
// row=(lane>>4)*4+reg.
__device__ __forceinline__ void gemm_tile(
    const float* __restrict__ A, const u16* __restrict__ Bfh,
    const u16* __restrict__ Bfl, const float* __restrict__ dis,
    float* __restrict__ C, int N, int K, int tile,
    u16* AsH, u16* AsL) {
    const int tid = threadIdx.x;
    const int w = tid >> 6, lane = tid & 63;
    const int m16 = lane & 15, quad = lane >> 4;
    const int row0 = tile * 64;

    const int s_ar = w * 16 + (lane & 15);
    const int s_ak = (lane >> 4) * 8;
    const int a_dst = TILE_OFF(w) + lane * 8;

    const int R = (w >> 1) * 32, Cc = (w & 1) * 64;
    const int atile = (w >> 1) * 2;
    const int btile = (w & 1) * 4;

    const int ksteps = K >> 5;
    const u16* bfh = Bfh + ((size_t)btile * ksteps) * 512 + lane * 8;
    const u16* bfl = Bfl + ((size_t)btile * ksteps) * 512 + lane * 8;

    f32x4 acc[2][4];
#pragma unroll
    for (int i = 0; i < 2; ++i)
#pragma unroll
        for (int j = 0; j < 4; ++j) acc[i][j] = (f32x4)0.f;

    float dr[2][4];
#pragma unroll
    for (int i = 0; i < 2; ++i)
#pragma unroll
        for (int r = 0; r < 4; ++r) {
            int gr = row0 + R + i * 16 + quad * 4 + r;
            dr[i][r] = dis[gr < N ? gr : N - 1];
        }

    const int grow = row0 + s_ar;
    const bool ok = (grow < N);
    const float* aptr = A + (size_t)grow * K + s_ak;

    float av[8];
    {
        f32x4 v0 = (f32x4)0.f, v1 = (f32x4)0.f;
        if (ok) { v0 = *(const f32x4*)&aptr[0]; v1 = *(const f32x4*)&aptr[4]; }
#pragma unroll
        for (int q = 0; q < 4; ++q) { av[q] = v0[q]; av[4 + q] = v1[q]; }
    }

    for (int ks = 0; ks < ksteps; ++ks) {
        short8 fbh[4], fbl[4];
#pragma unroll
        for (int j = 0; j < 4; ++j) {
            fbh[j] = *(const short8*)(bfh + (size_t)(j * ksteps + ks) * 512);
            fbl[j] = *(const short8*)(bfl + (size_t)(j * ksteps + ks) * 512);
        }

        short8 ah, al;
#pragma unroll
        for (int q = 0; q < 8; ++q) {
            u16 h, l;
            split_bf16(av[q], h, l);
            ah[q] = (short)h;
            al[q] = (short)l;
        }
        __syncthreads();
        *(short8*)&AsH[a_dst] = ah;
        *(short8*)&AsL[a_dst] = al;
        __syncthreads();

        if (ks + 1 < ksteps) {
            const int k0 = (ks + 1) * 32;
            f32x4 v0 = (f32x4)0.f, v1 = (f32x4)0.f;
            if (ok) { v0 = *(const f32x4*)&aptr[k0]; v1 = *(const f32x4*)&aptr[k0 + 4]; }
#pragma unroll
            for (int q = 0; q < 4; ++q) { av[q] = v0[q]; av[4 + q] = v1[q]; }
        }

        short8 fah[2], fal[2];
#pragma unroll
        for (int i = 0; i < 2; ++i) {
            fah[i] = *(const short8*)&AsH[TILE_OFF(atile + i) + lane * 8];
            fal[i] = *(const short8*)&AsL[TILE_OFF(atile + i) + lane * 8];
        }

#pragma unroll
        for (int i = 0; i < 2; ++i)
#pragma unroll
            for (int j = 0; j < 4; ++j) {
                acc[i][j] = __builtin_amdgcn_mfma_f32_16x16x32_bf16(
                    fah[i], fbh[j], acc[i][j], 0, 0, 0);
                acc[i][j] = __builtin_amdgcn_mfma_f32_16x16x32_bf16(
                    fah[i], fbl[j], acc[i][j], 0, 0, 0);
                acc[i][j] = __builtin_amdgcn_mfma_f32_16x16x32_bf16(
                    fal[i], fbh[j], acc[i][j], 0, 0, 0);
            }
    }

#pragma unroll
    for (int i = 0; i < 2; ++i) {
#pragma unroll
        for (int r = 0; r < 4; ++r) {
            int gr = row0 + R + i * 16 + quad * 4 + r;
            if (gr < N) {
#pragma unroll
                for (int j = 0; j < 4; ++j)
                    C[(size_t)gr * 128 + Cc + j * 16 + m16] = acc[i][j][r] * dr[i][r];
            }
        }
    }
}

// ---- K1: weight conversion (frag order) + degree count --------------------
__global__ void conv_deg_kernel(
    const float* __restrict__ W1, const float* __restrict__ W2,
    const float* __restrict__ Wm, const float* __restrict__ Ws,
    u16* __restrict__ B1h, u16* __restrict__ B1l,
    u16* __restrict__ B2h, u16* __restrict__ B2l,
    u16* __restrict__ Bch, u16* __restrict__ Bcl,
    const int* __restrict__ ew, int* __restrict__ deg, int E) {
    __shared__ int sflag;
    int mode = block_mode(ew, &sflag);
    int gtid = blockIdx.x * 256 + threadIdx.x;
    if (gtid < 98304) {
        int idx = gtid;
        u16 h, l;
        if (idx < 65536) {                 // W1: 512x128, ksteps=16
            int t = idx >> 13, ks = (idx >> 9) & 15, L = (idx >> 3) & 63, q = idx & 7;
            int col = t * 16 + (L & 15);
            int k = ks * 32 + (L >> 4) * 8 + q;
            split_bf16(W1[k * 128 + col], h, l);
            B1h[idx] = h; B1l[idx] = l;
        } else if (idx < 81920) {          // W2: 128x128, ksteps=4
            int o = idx - 65536;
            int t = o >> 11, ks = (o >> 9) & 3, L = (o >> 3) & 63, q = o & 7;
            int col = t * 16 + (L & 15);
            int k = ks * 32 + (L >> 4) * 8 + q;
            split_bf16(W2[k * 128 + col], h, l);
            B2h[o] = h; B2l[o] = l;
        } else {                           // [Wm|Ws]: 128x128, ksteps=4
            int o = idx - 81920;
            int t = o >> 11, ks = (o >> 9) & 3, L = (o >> 3) & 63, q = o & 7;
            int col = t * 16 + (L & 15);
            int k = ks * 32 + (L >> 4) * 8 + q;
            float f = (col < 64) ? Wm[k * 64 + col] : Ws[k * 64 + (col - 64)];
            split_bf16(f, h, l);
            Bch[o] = h; Bcl[o] = l;
        }
    }
    if (gtid < E) {
        int d = mode ? ew[2 * E + 2 * gtid] : ew[E + gtid];
        atomicAdd(&deg[d], 1);
    }
}

// ---- K2: per-chunk exclusive scan + dis = rsqrt(deg+1) --------------------
__global__ void scan_block_kernel(const int* __restrict__ deg, int* __restrict__ rowptr,
                                  int* __restrict__ aux, float* __restrict__ dis, int N) {
    __shared__ int s[256];
    int i = blockIdx.x * 256 + threadIdx.x;
    int v = (i < N) ? deg[i] : 0;
    if (i < N) dis[i] = rsqrtf((float)v + 1.0f);
    s[threadIdx.x] = v;
    __syncthreads();
    for (int off = 1; off < 256; off <<= 1) {
        int t = (threadIdx.x >= off) ? s[threadIdx.x - off] : 0;
        __syncthreads();
        s[threadIdx.x] += t;
        __syncthreads();
    }
    if (i < N) rowptr[i] = s[threadIdx.x] - v;
    if (threadIdx.x == 255) aux[blockIdx.x] = s[255];
}

// ---- K3: offsets with inline aux scan + cursor init -----------------------
// Each block redundantly scans aux[0..nch) in LDS (nch <= 256), then applies
// the exclusive prefix for its own chunk b (= s[b-1]).
__global__ void offsets_kernel(int* __restrict__ rowptr, const int* __restrict__ aux,
                               int* __restrict__ cursor, int N, int E, int nch) {
    __shared__ int s[256];
    const int b = blockIdx.x, tid = threadIdx.x;
    int v = (tid < nch) ? aux[tid] : 0;
    s[tid] = v;
    __syncthreads();
    for (int off = 1; off < 256; off <<= 1) {
        int t = (tid >= off) ? s[tid - off] : 0;
        __syncthreads();
        s[tid] += t;
        __syncthreads();
    }
    const int excl = (b == 0) ? 0 : s[b - 1];     // LDS broadcast
    int i = b * 256 + tid;
    if (i < N) {
        int rp = rowptr[i] + excl;
        rowptr[i] = rp;
        cursor[i] = rp;
    }
    if (b == 0 && tid == 0) rowptr[N] = E;
}

// ---- K4: gemm1 (blocks < gtiles) PARALLEL fill_csr (remaining blocks) -----
__global__ __launch_bounds__(256) void gemm1_fill_kernel(
    const float* __restrict__ A, const u16* __restrict__ Bfh,
    const u16* __restrict__ Bfl, const float* __restrict__ dis,
    float* __restrict__ C, int N, int gtiles,
    const int* __restrict__ ew, int* __restrict__ cursor,
    int* __restrict__ csr_src, int E) {
    __shared__ __align__(16) u16 AsH[4 * 520], AsL[4 * 520];
    __shared__ int sflag;
    if ((int)blockIdx.x < gtiles) {
        gemm_tile(A, Bfh, Bfl, dis, C, N, 512, blockIdx.x, AsH, AsL);
    } else {
        int mode = block_mode(ew, &sflag);
        int e = ((int)blockIdx.x - gtiles) * 256 + (int)threadIdx.x;
        if (e < E) {
            int s = mode ? ew[2 * e] : ew[e];
            int d = mode ? ew[2 * E + 2 * e] : ew[E + e];
            int pos = atomicAdd(&cursor[d], 1);
            csr_src[pos] = s;
        }
    }
}

// ---- standalone GEMM (gemm2/gemm3) ----------------------------------------
__global__ __launch_bounds__(256) void gemm_mfma(const float* __restrict__ A,
                                                 const u16* __restrict__ Bfh,
                                                 const u16* __restrict__ Bfl,
                                                 const float* __restrict__ dis,
                                                 float* __restrict__ C,
                                                 int N, int K) {
    __shared__ __align__(16) u16 AsH[4 * 520], AsL[4 * 520];
    gemm_tile(A, Bfh, Bfl, dis, C, N, K, blockIdx.x, AsH, AsL);
}

// ---- propagate: one wave per node, paired-edge float4 gather --------------
// hs = dis (.) (A*W). out[v] = relu?( dis[v]*(sum_src hs[src] + hs[v]) + b ).
__global__ __launch_bounds__(256) void propagate_kernel(
    const float* __restrict__ hs, const int* __restrict__ rowptr,
    const int* __restrict__ csr_src, const float* __restrict__ dis,
    const float* __restrict__ bias, float* __restrict__ out, int N, int do_relu) {
    int wave = (blockIdx.x * 256 + threadIdx.x) >> 6;
    int lane = threadIdx.x & 63;
    if (wave >= N) return;
    const int v = wave;
    const int half = lane >> 5, c = lane & 31;
    const int f4 = c * 4;
    const float dv = dis[v];
    f32x4 acc = (f32x4)0.f;
    const int beg = rowptr[v], end = rowptr[v + 1];
    int i = beg;
    for (; i + 8 <= end; i += 8) {
        int s[4];
        f32x4 g[4];
#pragma unroll
        for (int u = 0; u < 4; ++u) s[u] = csr_src[i + 2 * u + half];
#pragma unroll
        for (int u = 0; u < 4; ++u) g[u] = *(const f32x4*)&hs[(size_t)s[u] * 128 + f4];
#pragma unroll
        for (int u = 0; u < 4; ++u) acc += g[u];
    }
    for (; i + 2 <= end; i += 2) {
        int s = csr_src[i + half];
        acc += *(const f32x4*)&hs[(size_t)s * 128 + f4];
    }
    if (i < end && half == 0) {
        int s = csr_src[i];
        acc += *(const f32x4*)&hs[(size_t)s * 128 + f4];
    }
#pragma unroll
    for (int k = 0; k < 4; ++k) acc[k] += __shfl_xor(acc[k], 32);
    if (half == 0) {
        const f32x4 hv = *(const f32x4*)&hs[(size_t)v * 128 + f4];
        const f32x4 b = *(const f32x4*)&bias[f4];
        f32x4 o;
#pragma unroll
        for (int k = 0; k < 4; ++k) {
            float t = dv * (acc[k] + hv[k]) + b[k];
            o[k] = do_relu ? fmaxf(t, 0.f) : t;
        }
        *(f32x4*)&out[(size_t)v * 128 + f4] = o;
    }
}

// ---- final propagate: split into z_mean / z_log_std -----------------------
__global__ void __launch_bounds__(256) propagate_final_kernel(
    const float* __restrict__ hs, const int* __restrict__ rowptr,
    const int* __restrict__ csr_src, const float* __restrict__ dis,
    const float* __restrict__ bm, const float* __restrict__ bs,
    float* __restrict__ out, int N) {
    int wave = (blockIdx.x * 256 + threadIdx.x) >> 6;
    int lane = threadIdx.x & 63;
    if (wave >= N) return;
    const int v = wave;
    const int half = lane >> 5, c = lane & 31;
    const int f4 = c * 4;
    const float dv = dis[v];
    f32x4 acc = (f32x4)0.f;
    const int beg = rowptr[v], end = rowptr[v + 1];
    int i = beg;
    for (; i + 8 <= end; i += 8) {
        int s[4];
        f32x4 g[4];
#pragma unroll
        for (int u = 0; u < 4; ++u) s[u] = csr_src[i + 2 * u + half];
#pragma unroll
        for (int u = 0; u < 4; ++u) g[u] = *(const f32x4*)&hs[(size_t)s[u] * 128 + f4];
#pragma unroll
        for (int u = 0; u < 4; ++u) acc += g[u];
    }
    for (; i + 2 <= end; i += 2) {
        int s = csr_src[i + half];
        acc += *(const f32x4*)&hs[(size_t)s * 128 + f4];
    }
    if (i < end && half == 0) {
        int s = csr_src[i];
        acc += *(const f32x4*)&hs[(size_t)s * 128 + f4];
    }
#pragma unroll
    for (int k = 0; k < 4; ++k) acc[k] += __shfl_xor(acc[k], 32);
    if (half == 0) {
        const f32x4 hv = *(const f32x4*)&hs[(size_t)v * 128 + f4];
        f32x4 o;
        if (f4 < 64) {                          // z_mean
            const f32x4 b = *(const f32x4*)&bm[f4];
#pragma unroll
            for (int k = 0; k < 4; ++k) o[k] = dv * (acc[k] + hv[k]) + b[k];
            *(f32x4*)&out[(size_t)v * 64 + f4] = o;
        } else {                                // z_log_std
            const int g = f4 - 64;
            const f32x4 b = *(const f32x4*)&bs[g];
#pragma unroll
            for (int k = 0; k < 4; ++k) o[k] = dv * (acc[k] + hv[k]) + b[k];
            *(f32x4*)&out[(size_t)N * 64 + (size_t)v * 64 + g] = o;
        }
    }
}

extern "C" void kernel_launch(void* const* d_in, const int* in_sizes, int n_in,
                              void* d_out, int out_size, void* d_ws, size_t ws_size,
                              hipStream_t stream) {
    const float* x  = (const float*)d_in[0];
    const int*   ew = (const int*)d_in[1];
    const float* W1 = (const float*)d_in[2];
    const float* b1 = (const float*)d_in[3];
    const float* W2 = (const float*)d_in[4];
    const float* b2 = (const float*)d_in[5];
    const float* Wm = (const float*)d_in[6];
    const float* bm = (const float*)d_in[7];
    const float* Ws = (const float*)d_in[8];
    const float* bs = (const float*)d_in[9];
    float* out = (float*)d_out;

    const int IN = 512, H = 128;
    const int N = in_sizes[0] / IN;     // 50000
    const int E = in_sizes[1] / 2;      // 800000

    // ---- workspace (~55.6 MB < proven-safe 58.47 MB) -----------------------
    char* base = (char*)d_ws;
    size_t off = 0;
    auto alloc = [&](size_t bytes) -> char* {
        char* p = base + off;
        off = (off + bytes + 255) & ~(size_t)255;
        return p;
    };
    int*   deg     = (int*)  alloc((size_t)N * 4);      // zeroed
    int*   cursor  = (int*)  alloc((size_t)N * 4);      // init in offsets
    float* dis     = (float*)alloc((size_t)N * 4);
    int*   rowptr  = (int*)  alloc((size_t)(N + 1) * 4);
    int*   aux     = (int*)  alloc(256 * 4);
    int*   csr_src = (int*)  alloc((size_t)E * 4);
    u16*   B1h     = (u16*)  alloc((size_t)IN * H * 2);
    u16*   B1l     = (u16*)  alloc((size_t)IN * H * 2);
    u16*   B2h     = (u16*)  alloc((size_t)H * H * 2);
    u16*   B2l     = (u16*)  alloc((size_t)H * H * 2);
    u16*   Bch     = (u16*)  alloc((size_t)H * H * 2);
    u16*   Bcl     = (u16*)  alloc((size_t)H * H * 2);
    float* hA      = (float*)alloc((size_t)N * H * 4);
    float* hB      = (float*)alloc((size_t)N * H * 4);
    (void)ws_size; (void)n_in; (void)out_size;

    hipMemsetAsync(deg, 0, (size_t)N * 4, stream);

    const int eblocks = (E + 255) / 256;
    const int nblocks = (N + 255) / 256;
    const int nch = nblocks;                      // chunks of 256 (<= 256)
    const int gtiles = (N + 63) / 64;
    const int pblocks = (N * 64 + 255) / 256;

    // K1: conv + deg (independent work, one dispatch)
    conv_deg_kernel<<<eblocks, 256, 0, stream>>>(
        W1, W2, Wm, Ws, B1h, B1l, B2h, B2l, Bch, Bcl, ew, deg, E);
    // K2: chunk scan + dis
    scan_block_kernel<<<nblocks, 256, 0, stream>>>(deg, rowptr, aux, dis, N);
    // K3: offsets (inline aux scan) + cursor init
    offsets_kernel<<<nblocks, 256, 0, stream>>>(rowptr, aux, cursor, N, E, nch);
    // K4: gemm1 || fill_csr (mixed-role grid)
    gemm1_fill_kernel<<<gtiles + eblocks, 256, 0, stream>>>(
        x, B1h, B1l, dis, hA, N, gtiles, ew, cursor, csr_src, E);
    // K5..K9
    propagate_kernel<<<pblocks, 256, 0, stream>>>(hA, rowptr, csr_src, dis,
                                                  b1, hB, N, 1);
    gemm_mfma<<<gtiles, 256, 0, stream>>>(hB, B2h, B2l, dis, hA, N, H);
    propagate_kernel<<<pblocks, 256, 0, stream>>>(hA, rowptr, csr_src, dis,
                                                  b2, hB, N, 1);
    gemm_mfma<<<gtiles, 256, 0, stream>>>(hB, Bch, Bcl, dis, hA, N, H);
    propagate_final_kernel<<<pblocks, 256, 0, stream>>>(hA, rowptr, csr_src, dis,
                                                        bm, bs, out, N);
}